// Round 2
// baseline (929.676 us; speedup 1.0000x reference)
//
#include <hip/hip_runtime.h>
#include <hip/hip_bf16.h>

#define NNODES 100000
#define NEDGES 1600000
#define NHEADS 4
#define NGRAPH 64
#define NOUTF  32

// ---------------- index dtype detect + convert ----------------
// If edge_index arrived as int64 (little-endian, values < 2^31), every odd
// 32-bit word is zero. Random int32 indices make that statistically impossible.
__global__ void gat_detect_kernel(const int* __restrict__ raw, int* __restrict__ flag) {
    __shared__ int any;
    if (threadIdx.x == 0) any = 0;
    __syncthreads();
    int w = raw[threadIdx.x * 2 + 1];   // odd words among first 2048
    if (w != 0) any = 1;                // benign race
    __syncthreads();
    if (threadIdx.x == 0) flag[0] = (any == 0) ? 1 : 0;   // 1 => int64
}

__global__ void gat_cvt_kernel(const int* __restrict__ ei, const int* __restrict__ bt,
                               const int* __restrict__ flag, int* __restrict__ src,
                               int* __restrict__ dst, int* __restrict__ bat, int ne, int n) {
    int i = blockIdx.x * blockDim.x + threadIdx.x;
    bool wide = flag[0] != 0;
    if (i < ne) {
        src[i] = wide ? ei[2 * i] : ei[i];
        dst[i] = wide ? ei[2 * (ne + i)] : ei[ne + i];
    }
    if (i < n) bat[i] = wide ? bt[2 * i] : bt[i];
}

// ---------------- CSR build ----------------
__global__ void gat_hist_kernel(const int* __restrict__ dst, int* __restrict__ deg, int ne) {
    int e = blockIdx.x * blockDim.x + threadIdx.x;
    if (e < ne) atomicAdd(&deg[dst[e]], 1);
}

__global__ void gat_scan1_kernel(const int* __restrict__ deg, int* __restrict__ incl,
                                 int* __restrict__ bsum, int n) {
    __shared__ int sh[1024];
    int i = blockIdx.x * 1024 + threadIdx.x;
    int v = (i < n) ? deg[i] : 0;
    sh[threadIdx.x] = v;
    __syncthreads();
    for (int off = 1; off < 1024; off <<= 1) {
        int t = (threadIdx.x >= off) ? sh[threadIdx.x - off] : 0;
        __syncthreads();
        sh[threadIdx.x] += t;
        __syncthreads();
    }
    if (i < n) incl[i] = sh[threadIdx.x];
    if (threadIdx.x == 1023) bsum[blockIdx.x] = sh[1023];
}

__global__ void gat_scan2_kernel(int* bsum, int nb) {
    __shared__ int sh[128];
    int v = (threadIdx.x < nb) ? bsum[threadIdx.x] : 0;
    sh[threadIdx.x] = v;
    __syncthreads();
    for (int off = 1; off < 128; off <<= 1) {
        int t = (threadIdx.x >= off) ? sh[threadIdx.x - off] : 0;
        __syncthreads();
        sh[threadIdx.x] += t;
        __syncthreads();
    }
    if (threadIdx.x < nb) bsum[threadIdx.x] = sh[threadIdx.x] - v;  // exclusive
}

__global__ void gat_scan3_kernel(const int* __restrict__ deg, const int* __restrict__ incl,
                                 const int* __restrict__ bsum, int* __restrict__ row_ptr,
                                 int* __restrict__ cursor, int n) {
    int i = blockIdx.x * blockDim.x + threadIdx.x;
    if (i < n) {
        int inc = incl[i] + bsum[i >> 10];
        int ex = inc - deg[i];
        row_ptr[i] = ex;
        cursor[i] = ex;
        if (i == n - 1) row_ptr[n] = inc;
    }
}

__global__ void gat_scatter_kernel(const int* __restrict__ src, const int* __restrict__ dst,
                                   int* __restrict__ cursor, int* __restrict__ col, int ne) {
    int e = blockIdx.x * blockDim.x + threadIdx.x;
    if (e < ne) {
        int pos = atomicAdd(&cursor[dst[e]], 1);
        col[pos] = src[e];
    }
}

// ---------------- GEMM + attention coefficients ----------------
// h = in @ W  (N x DIN) x (DIN x DOUT), plus al_s/al_d = per-head dot with a_src/a_dst
template<int DIN, int DOUT, int PASSES>
__global__ __launch_bounds__(256) void gat_gemm_attn_kernel(
        const float* __restrict__ in, const float* __restrict__ W,
        const float* __restrict__ a_src, const float* __restrict__ a_dst,
        float* __restrict__ h, float* __restrict__ al_s, float* __restrict__ al_d, int n) {
    constexpr int NPP = 256 / DOUT;      // nodes per pass
    constexpr int C = DOUT / NHEADS;     // channels per head
    __shared__ float Wl[DIN * DOUT];
    __shared__ float xs[NPP][DIN + 1];
    int tid = threadIdx.x;
    for (int i = tid; i < DIN * DOUT; i += 256) Wl[i] = W[i];
    int oc = tid % DOUT;
    int sub = tid / DOUT;
    float a_s = a_src[oc];
    float a_d = a_dst[oc];
    int base = blockIdx.x * (NPP * PASSES);
    for (int p = 0; p < PASSES; p++) {
        int node0 = base + p * NPP;
        __syncthreads();
        for (int i = tid; i < NPP * DIN; i += 256) {
            int nn = i / DIN, kk = i - nn * DIN;
            int nd = node0 + nn;
            xs[nn][kk] = (nd < n) ? in[nd * DIN + kk] : 0.f;
        }
        __syncthreads();
        int node = node0 + sub;
        if (node < n) {
            float acc = 0.f;
            #pragma unroll
            for (int k = 0; k < DIN; k++) acc += xs[sub][k] * Wl[k * DOUT + oc];
            h[node * DOUT + oc] = acc;
            float vs = acc * a_s, vd = acc * a_d;
            #pragma unroll
            for (int off = 1; off < C; off <<= 1) {
                vs += __shfl_xor(vs, off);
                vd += __shfl_xor(vd, off);
            }
            if ((oc & (C - 1)) == 0) {
                int hh = oc / C;
                al_s[node * NHEADS + hh] = vs;
                al_d[node * NHEADS + hh] = vd;
            }
        }
    }
}

// ---------------- per-destination-node softmax aggregation ----------------
// one wave per node; lanes tile (head, channel); groups of G lanes strip-mine edges
template<int C>
__global__ __launch_bounds__(256) void gat_agg_kernel(
        const float* __restrict__ h, const float* __restrict__ al_s, const float* __restrict__ al_d,
        const int* __restrict__ row_ptr, const int* __restrict__ col,
        const float* __restrict__ bias, float* __restrict__ out, int n) {
    constexpr int G = NHEADS * C;  // row width
    constexpr int NG = 64 / G;     // edge groups per wave
    int lane = threadIdx.x & 63;
    int node = blockIdx.x * 4 + (threadIdx.x >> 6);
    if (node >= n) return;
    int j = lane & (G - 1);
    int g = lane / G;
    int hh = j / C;
    int beg = row_ptr[node], end = row_ptr[node + 1];
    float ald = al_d[node * NHEADS + hh];
    float acc = 0.f, ssum = 0.f;
    int cnt = end - beg;
    // t == cnt is the implicit self-loop (PyG add_self_loops)
    for (int t = g; t < cnt + 1; t += NG) {
        int src = (t < cnt) ? col[beg + t] : node;
        float e = al_s[src * NHEADS + hh] + ald;
        e = (e > 0.f) ? e : 0.2f * e;           // leaky_relu(0.2)
        float w = __expf(e);                    // no max-shift needed: |e| small
        ssum += w;
        acc += w * h[src * G + j];
    }
    #pragma unroll
    for (int off = G; off < 64; off <<= 1) {
        acc += __shfl_xor(acc, off);
        ssum += __shfl_xor(ssum, off);
    }
    if (lane < G) {
        float v = acc / (ssum + 1e-16f) + bias[j];
        out[node * G + j] = (v > 0.f) ? v : 0.f;   // relu
    }
}

// ---------------- pooling + FC ----------------
__global__ void gat_pool_kernel(const float* __restrict__ x, const int* __restrict__ batch,
                                float* __restrict__ gsum, int* __restrict__ gcnt, int n) {
    __shared__ float bins[NGRAPH * 8];
    __shared__ int cbin[NGRAPH];
    int tid = threadIdx.x;
    for (int i = tid; i < NGRAPH * 8; i += 256) bins[i] = 0.f;
    if (tid < NGRAPH) cbin[tid] = 0;
    __syncthreads();
    int node = blockIdx.x * 256 + tid;
    if (node < n) {
        int b = batch[node];
        atomicAdd(&cbin[b], 1);
        for (int d = 0; d < 8; d++) atomicAdd(&bins[b * 8 + d], x[node * 8 + d]);
    }
    __syncthreads();
    for (int i = tid; i < NGRAPH * 8; i += 256)
        if (bins[i] != 0.f) atomicAdd(&gsum[i], bins[i]);
    if (tid < NGRAPH && cbin[tid]) atomicAdd(&gcnt[tid], cbin[tid]);
}

__global__ void gat_fc_kernel(const float* __restrict__ gsum, const int* __restrict__ gcnt,
                              const float* __restrict__ Wfc, const float* __restrict__ bfc,
                              float* __restrict__ out) {
    int idx = blockIdx.x * 256 + threadIdx.x;
    if (idx >= NGRAPH * NOUTF) return;
    int b = idx / NOUTF, o = idx % NOUTF;
    float c = (float)gcnt[b];
    if (c < 1.f) c = 1.f;
    float acc = bfc[o];
    #pragma unroll
    for (int d = 0; d < 8; d++) acc += (gsum[b * 8 + d] / c) * Wfc[d * NOUTF + o];
    out[idx] = acc;
}

extern "C" void kernel_launch(void* const* d_in, const int* in_sizes, int n_in,
                              void* d_out, int out_size, void* d_ws, size_t ws_size,
                              hipStream_t stream) {
    const float* x = (const float*)d_in[0];
    const int* ei = (const int*)d_in[1];          // [2, E]: row0 = src, row1 = dst
    const int* batch = (const int*)d_in[2];
    const float* W1 = (const float*)d_in[3];
    const float* as1 = (const float*)d_in[4];
    const float* ad1 = (const float*)d_in[5];
    const float* b1 = (const float*)d_in[6];
    const float* W2 = (const float*)d_in[7];
    const float* as2 = (const float*)d_in[8];
    const float* ad2 = (const float*)d_in[9];
    const float* b2 = (const float*)d_in[10];
    const float* W3 = (const float*)d_in[11];
    const float* as3 = (const float*)d_in[12];
    const float* ad3 = (const float*)d_in[13];
    const float* b3 = (const float*)d_in[14];
    const float* W4 = (const float*)d_in[15];
    const float* as4 = (const float*)d_in[16];
    const float* ad4 = (const float*)d_in[17];
    const float* b4 = (const float*)d_in[18];
    const float* Wfc = (const float*)d_in[19];
    const float* bfc = (const float*)d_in[20];

    const int n = NNODES, ne = NEDGES;

    // workspace carve (256B aligned)
    char* p = (char*)d_ws;
    auto carve = [&](size_t bytes) {
        char* r = p;
        p += (bytes + 255) & ~(size_t)255;
        return r;
    };
    int* deg = (int*)carve((size_t)n * 4);
    int* cursor = (int*)carve((size_t)n * 4);
    int* row_ptr = (int*)carve((size_t)(n + 1) * 4);
    int* col = (int*)carve((size_t)ne * 4);
    int* incl = (int*)carve((size_t)n * 4);
    int* bsum = (int*)carve(128 * 4);
    float* buf_h = (float*)carve((size_t)n * 64 * 4);
    float* buf_x = (float*)carve((size_t)n * 64 * 4);
    float* al_s = (float*)carve((size_t)n * NHEADS * 4);
    float* al_d = (float*)carve((size_t)n * NHEADS * 4);
    float* gsum = (float*)carve(NGRAPH * 8 * 4);
    int* gcnt = (int*)carve(NGRAPH * 4);
    int* bat = (int*)carve((size_t)n * 4);
    int* flag = (int*)carve(256);
    // src/dst alias buf_h: consumed by hist/scatter strictly before gemm1 writes buf_h
    int* srcv = (int*)buf_h;
    int* dstv = srcv + ne;

    hipMemsetAsync(deg, 0, (size_t)n * 4, stream);
    hipMemsetAsync(gsum, 0, NGRAPH * 8 * 4, stream);
    hipMemsetAsync(gcnt, 0, NGRAPH * 4, stream);

    // normalize index dtype (int32 vs int64) into srcv/dstv/bat
    gat_detect_kernel<<<1, 1024, 0, stream>>>(ei, flag);
    gat_cvt_kernel<<<(ne + 255) / 256, 256, 0, stream>>>(ei, batch, flag, srcv, dstv, bat, ne, n);

    // CSR by destination, built once, reused by all 4 layers
    gat_hist_kernel<<<(ne + 255) / 256, 256, 0, stream>>>(dstv, deg, ne);
    int nblk = (n + 1023) / 1024;
    gat_scan1_kernel<<<nblk, 1024, 0, stream>>>(deg, incl, bsum, n);
    gat_scan2_kernel<<<1, 128, 0, stream>>>(bsum, nblk);
    gat_scan3_kernel<<<(n + 255) / 256, 256, 0, stream>>>(deg, incl, bsum, row_ptr, cursor, n);
    gat_scatter_kernel<<<(ne + 255) / 256, 256, 0, stream>>>(srcv, dstv, cursor, col, ne);

    // layer 1: 128 -> 4x16
    gat_gemm_attn_kernel<128, 64, 16><<<(n + 63) / 64, 256, 0, stream>>>(
        x, W1, as1, ad1, buf_h, al_s, al_d, n);
    gat_agg_kernel<16><<<(n + 3) / 4, 256, 0, stream>>>(buf_h, al_s, al_d, row_ptr, col, b1, buf_x, n);

    // layer 2: 64 -> 4x8
    gat_gemm_attn_kernel<64, 32, 16><<<(n + 127) / 128, 256, 0, stream>>>(
        buf_x, W2, as2, ad2, buf_h, al_s, al_d, n);
    gat_agg_kernel<8><<<(n + 3) / 4, 256, 0, stream>>>(buf_h, al_s, al_d, row_ptr, col, b2, buf_x, n);

    // layer 3: 32 -> 4x4
    gat_gemm_attn_kernel<32, 16, 16><<<(n + 255) / 256, 256, 0, stream>>>(
        buf_x, W3, as3, ad3, buf_h, al_s, al_d, n);
    gat_agg_kernel<4><<<(n + 3) / 4, 256, 0, stream>>>(buf_h, al_s, al_d, row_ptr, col, b3, buf_x, n);

    // layer 4: 16 -> 4x2
    gat_gemm_attn_kernel<16, 8, 16><<<(n + 511) / 512, 256, 0, stream>>>(
        buf_x, W4, as4, ad4, buf_h, al_s, al_d, n);
    gat_agg_kernel<2><<<(n + 3) / 4, 256, 0, stream>>>(buf_h, al_s, al_d, row_ptr, col, b4, buf_x, n);

    // global mean pool + FC
    gat_pool_kernel<<<(n + 255) / 256, 256, 0, stream>>>(buf_x, bat, gsum, gcnt, n);
    gat_fc_kernel<<<8, 256, 0, stream>>>(gsum, gcnt, Wfc, bfc, (float*)d_out);
}

// Round 3
// 734.435 us; speedup vs baseline: 1.2658x; 1.2658x over previous
//
#include <hip/hip_runtime.h>
#include <hip/hip_bf16.h>

#define NNODES 100000
#define NEDGES 1600000
#define NHEADS 4
#define NGRAPH 64
#define NOUTF  32

// ---------------- index dtype detect + convert ----------------
// If edge_index arrived as int64 (little-endian, values < 2^31), every odd
// 32-bit word is zero. Random int32 indices make that statistically impossible.
__global__ void gat_detect_kernel(const int* __restrict__ raw, int* __restrict__ flag) {
    __shared__ int any;
    if (threadIdx.x == 0) any = 0;
    __syncthreads();
    int w = raw[threadIdx.x * 2 + 1];   // odd words among first 2048
    if (w != 0) any = 1;                // benign race
    __syncthreads();
    if (threadIdx.x == 0) flag[0] = (any == 0) ? 1 : 0;   // 1 => int64
}

__global__ void gat_cvt_kernel(const int* __restrict__ ei, const int* __restrict__ bt,
                               const int* __restrict__ flag, int* __restrict__ src,
                               int* __restrict__ dst, int* __restrict__ bat, int ne, int n) {
    int i = blockIdx.x * blockDim.x + threadIdx.x;
    bool wide = flag[0] != 0;
    if (i < ne) {
        src[i] = wide ? ei[2 * i] : ei[i];
        dst[i] = wide ? ei[2 * (ne + i)] : ei[ne + i];
    }
    if (i < n) bat[i] = wide ? bt[2 * i] : bt[i];
}

// ---------------- CSR build ----------------
__global__ void gat_hist_kernel(const int* __restrict__ dst, int* __restrict__ deg, int ne) {
    int e = blockIdx.x * blockDim.x + threadIdx.x;
    if (e < ne) atomicAdd(&deg[dst[e]], 1);
}

__global__ void gat_scan1_kernel(const int* __restrict__ deg, int* __restrict__ incl,
                                 int* __restrict__ bsum, int n) {
    __shared__ int sh[1024];
    int i = blockIdx.x * 1024 + threadIdx.x;
    int v = (i < n) ? deg[i] : 0;
    sh[threadIdx.x] = v;
    __syncthreads();
    for (int off = 1; off < 1024; off <<= 1) {
        int t = (threadIdx.x >= off) ? sh[threadIdx.x - off] : 0;
        __syncthreads();
        sh[threadIdx.x] += t;
        __syncthreads();
    }
    if (i < n) incl[i] = sh[threadIdx.x];
    if (threadIdx.x == 1023) bsum[blockIdx.x] = sh[1023];
}

__global__ void gat_scan2_kernel(int* bsum, int nb) {
    __shared__ int sh[128];
    int v = (threadIdx.x < nb) ? bsum[threadIdx.x] : 0;
    sh[threadIdx.x] = v;
    __syncthreads();
    for (int off = 1; off < 128; off <<= 1) {
        int t = (threadIdx.x >= off) ? sh[threadIdx.x - off] : 0;
        __syncthreads();
        sh[threadIdx.x] += t;
        __syncthreads();
    }
    if (threadIdx.x < nb) bsum[threadIdx.x] = sh[threadIdx.x] - v;  // exclusive
}

__global__ void gat_scan3_kernel(const int* __restrict__ deg, const int* __restrict__ incl,
                                 const int* __restrict__ bsum, int* __restrict__ row_ptr,
                                 int* __restrict__ cursor, int n) {
    int i = blockIdx.x * blockDim.x + threadIdx.x;
    if (i < n) {
        int inc = incl[i] + bsum[i >> 10];
        int ex = inc - deg[i];
        row_ptr[i] = ex;
        cursor[i] = ex;
        if (i == n - 1) row_ptr[n] = inc;
    }
}

__global__ void gat_scatter_kernel(const int* __restrict__ src, const int* __restrict__ dst,
                                   int* __restrict__ cursor, int* __restrict__ col, int ne) {
    int e = blockIdx.x * blockDim.x + threadIdx.x;
    if (e < ne) {
        int pos = atomicAdd(&cursor[dst[e]], 1);
        col[pos] = src[e];
    }
}

// ---------------- GEMM + attention coefficients ----------------
// h = in @ W  (N x DIN) x (DIN x DOUT), plus al_s/al_d = per-head dot with a_src/a_dst
template<int DIN, int DOUT, int PASSES>
__global__ __launch_bounds__(256) void gat_gemm_attn_kernel(
        const float* __restrict__ in, const float* __restrict__ W,
        const float* __restrict__ a_src, const float* __restrict__ a_dst,
        float* __restrict__ h, float* __restrict__ al_s, float* __restrict__ al_d, int n) {
    constexpr int NPP = 256 / DOUT;      // nodes per pass
    constexpr int C = DOUT / NHEADS;     // channels per head
    __shared__ float Wl[DIN * DOUT];
    __shared__ float xs[NPP][DIN + 1];
    int tid = threadIdx.x;
    for (int i = tid; i < DIN * DOUT; i += 256) Wl[i] = W[i];
    int oc = tid % DOUT;
    int sub = tid / DOUT;
    float a_s = a_src[oc];
    float a_d = a_dst[oc];
    int base = blockIdx.x * (NPP * PASSES);
    for (int p = 0; p < PASSES; p++) {
        int node0 = base + p * NPP;
        __syncthreads();
        for (int i = tid; i < NPP * DIN; i += 256) {
            int nn = i / DIN, kk = i - nn * DIN;
            int nd = node0 + nn;
            xs[nn][kk] = (nd < n) ? in[nd * DIN + kk] : 0.f;
        }
        __syncthreads();
        int node = node0 + sub;
        if (node < n) {
            float acc = 0.f;
            #pragma unroll
            for (int k = 0; k < DIN; k++) acc += xs[sub][k] * Wl[k * DOUT + oc];
            h[node * DOUT + oc] = acc;
            float vs = acc * a_s, vd = acc * a_d;
            #pragma unroll
            for (int off = 1; off < C; off <<= 1) {
                vs += __shfl_xor(vs, off);
                vd += __shfl_xor(vd, off);
            }
            if ((oc & (C - 1)) == 0) {
                int hh = oc / C;
                al_s[node * NHEADS + hh] = vs;
                al_d[node * NHEADS + hh] = vd;
            }
        }
    }
}

// ---------------- per-destination-node softmax aggregation ----------------
// One wave per node. Row of G=NHEADS*C floats handled by L=G/4 lanes, each
// holding a float4 slice; NG=64/L edges are in flight per iteration (4x the
// scalar version's MLP for layer 1, with dwordx4 gathers instead of dword).
template<int C>
__global__ __launch_bounds__(256) void gat_agg_kernel(
        const float* __restrict__ h, const float* __restrict__ al_s, const float* __restrict__ al_d,
        const int* __restrict__ row_ptr, const int* __restrict__ col,
        const float* __restrict__ bias, float* __restrict__ out, int n) {
    constexpr int G = NHEADS * C;  // floats per row
    constexpr int L = G / 4;       // lanes per edge group (float4 each)
    constexpr int NG = 64 / L;     // edge groups in flight per wave
    int lane = threadIdx.x & 63;
    int node = blockIdx.x * 4 + (threadIdx.x >> 6);
    if (node >= n) return;
    int sub = lane & (L - 1);      // float4 index within row
    int g = lane / L;              // edge group id
    int c0 = sub * 4;              // first channel this lane covers
    int beg = row_ptr[node];
    int cnt = row_ptr[node + 1] - beg;
    // per-component dst attention (C==2: one float4 spans two heads)
    float ald0, ald1;
    if constexpr (C >= 4) {
        ald0 = al_d[node * NHEADS + c0 / C];
        ald1 = ald0;
    } else {
        ald0 = al_d[node * NHEADS + c0 / C];
        ald1 = al_d[node * NHEADS + (c0 + 2) / C];
    }
    const float4* h4 = (const float4*)h;
    float4 acc = make_float4(0.f, 0.f, 0.f, 0.f);
    float ws0 = 0.f, ws1 = 0.f;
    // t == cnt is the implicit self-loop (PyG add_self_loops)
    for (int t = g; t < cnt + 1; t += NG) {
        int src = (t < cnt) ? col[beg + t] : node;
        float4 hv = h4[src * L + sub];
        float w0, w1;
        if constexpr (C >= 4) {
            float e = al_s[src * NHEADS + c0 / C] + ald0;
            e = (e > 0.f) ? e : 0.2f * e;
            w0 = __expf(e);
            w1 = w0;
            ws0 += w0;
        } else {
            float e0 = al_s[src * NHEADS + c0 / C] + ald0;
            float e1 = al_s[src * NHEADS + (c0 + 2) / C] + ald1;
            e0 = (e0 > 0.f) ? e0 : 0.2f * e0;
            e1 = (e1 > 0.f) ? e1 : 0.2f * e1;
            w0 = __expf(e0);
            w1 = __expf(e1);
            ws0 += w0;
            ws1 += w1;
        }
        acc.x += w0 * hv.x;
        acc.y += w0 * hv.y;
        acc.z += w1 * hv.z;
        acc.w += w1 * hv.w;
    }
    // reduce across the NG edge groups
    #pragma unroll
    for (int off = L; off < 64; off <<= 1) {
        acc.x += __shfl_xor(acc.x, off);
        acc.y += __shfl_xor(acc.y, off);
        acc.z += __shfl_xor(acc.z, off);
        acc.w += __shfl_xor(acc.w, off);
        ws0 += __shfl_xor(ws0, off);
        if constexpr (C < 4) ws1 += __shfl_xor(ws1, off);
    }
    if (g == 0) {
        if constexpr (C >= 4) ws1 = ws0;
        float4 bv = ((const float4*)bias)[sub];
        float4 v;
        v.x = acc.x / (ws0 + 1e-16f) + bv.x;
        v.y = acc.y / (ws0 + 1e-16f) + bv.y;
        v.z = acc.z / (ws1 + 1e-16f) + bv.z;
        v.w = acc.w / (ws1 + 1e-16f) + bv.w;
        v.x = (v.x > 0.f) ? v.x : 0.f;
        v.y = (v.y > 0.f) ? v.y : 0.f;
        v.z = (v.z > 0.f) ? v.z : 0.f;
        v.w = (v.w > 0.f) ? v.w : 0.f;
        ((float4*)out)[node * L + sub] = v;
    }
}

// ---------------- pooling + FC ----------------
__global__ void gat_pool_kernel(const float* __restrict__ x, const int* __restrict__ batch,
                                float* __restrict__ gsum, int* __restrict__ gcnt, int n) {
    __shared__ float bins[NGRAPH * 8];
    __shared__ int cbin[NGRAPH];
    int tid = threadIdx.x;
    for (int i = tid; i < NGRAPH * 8; i += 256) bins[i] = 0.f;
    if (tid < NGRAPH) cbin[tid] = 0;
    __syncthreads();
    int node = blockIdx.x * 256 + tid;
    if (node < n) {
        int b = batch[node];
        atomicAdd(&cbin[b], 1);
        for (int d = 0; d < 8; d++) atomicAdd(&bins[b * 8 + d], x[node * 8 + d]);
    }
    __syncthreads();
    for (int i = tid; i < NGRAPH * 8; i += 256)
        if (bins[i] != 0.f) atomicAdd(&gsum[i], bins[i]);
    if (tid < NGRAPH && cbin[tid]) atomicAdd(&gcnt[tid], cbin[tid]);
}

__global__ void gat_fc_kernel(const float* __restrict__ gsum, const int* __restrict__ gcnt,
                              const float* __restrict__ Wfc, const float* __restrict__ bfc,
                              float* __restrict__ out) {
    int idx = blockIdx.x * 256 + threadIdx.x;
    if (idx >= NGRAPH * NOUTF) return;
    int b = idx / NOUTF, o = idx % NOUTF;
    float c = (float)gcnt[b];
    if (c < 1.f) c = 1.f;
    float acc = bfc[o];
    #pragma unroll
    for (int d = 0; d < 8; d++) acc += (gsum[b * 8 + d] / c) * Wfc[d * NOUTF + o];
    out[idx] = acc;
}

extern "C" void kernel_launch(void* const* d_in, const int* in_sizes, int n_in,
                              void* d_out, int out_size, void* d_ws, size_t ws_size,
                              hipStream_t stream) {
    const float* x = (const float*)d_in[0];
    const int* ei = (const int*)d_in[1];          // [2, E]: row0 = src, row1 = dst
    const int* batch = (const int*)d_in[2];
    const float* W1 = (const float*)d_in[3];
    const float* as1 = (const float*)d_in[4];
    const float* ad1 = (const float*)d_in[5];
    const float* b1 = (const float*)d_in[6];
    const float* W2 = (const float*)d_in[7];
    const float* as2 = (const float*)d_in[8];
    const float* ad2 = (const float*)d_in[9];
    const float* b2 = (const float*)d_in[10];
    const float* W3 = (const float*)d_in[11];
    const float* as3 = (const float*)d_in[12];
    const float* ad3 = (const float*)d_in[13];
    const float* b3 = (const float*)d_in[14];
    const float* W4 = (const float*)d_in[15];
    const float* as4 = (const float*)d_in[16];
    const float* ad4 = (const float*)d_in[17];
    const float* b4 = (const float*)d_in[18];
    const float* Wfc = (const float*)d_in[19];
    const float* bfc = (const float*)d_in[20];

    const int n = NNODES, ne = NEDGES;

    // workspace carve (256B aligned)
    char* p = (char*)d_ws;
    auto carve = [&](size_t bytes) {
        char* r = p;
        p += (bytes + 255) & ~(size_t)255;
        return r;
    };
    int* deg = (int*)carve((size_t)n * 4);
    int* cursor = (int*)carve((size_t)n * 4);
    int* row_ptr = (int*)carve((size_t)(n + 1) * 4);
    int* col = (int*)carve((size_t)ne * 4);
    int* incl = (int*)carve((size_t)n * 4);
    int* bsum = (int*)carve(128 * 4);
    float* buf_h = (float*)carve((size_t)n * 64 * 4);
    float* buf_x = (float*)carve((size_t)n * 64 * 4);
    float* al_s = (float*)carve((size_t)n * NHEADS * 4);
    float* al_d = (float*)carve((size_t)n * NHEADS * 4);
    float* gsum = (float*)carve(NGRAPH * 8 * 4);
    int* gcnt = (int*)carve(NGRAPH * 4);
    int* bat = (int*)carve((size_t)n * 4);
    int* flag = (int*)carve(256);
    // src/dst alias buf_h: consumed by hist/scatter strictly before gemm1 writes buf_h
    int* srcv = (int*)buf_h;
    int* dstv = srcv + ne;

    hipMemsetAsync(deg, 0, (size_t)n * 4, stream);
    hipMemsetAsync(gsum, 0, NGRAPH * 8 * 4, stream);
    hipMemsetAsync(gcnt, 0, NGRAPH * 4, stream);

    // normalize index dtype (int32 vs int64) into srcv/dstv/bat
    gat_detect_kernel<<<1, 1024, 0, stream>>>(ei, flag);
    gat_cvt_kernel<<<(ne + 255) / 256, 256, 0, stream>>>(ei, batch, flag, srcv, dstv, bat, ne, n);

    // CSR by destination, built once, reused by all 4 layers
    gat_hist_kernel<<<(ne + 255) / 256, 256, 0, stream>>>(dstv, deg, ne);
    int nblk = (n + 1023) / 1024;
    gat_scan1_kernel<<<nblk, 1024, 0, stream>>>(deg, incl, bsum, n);
    gat_scan2_kernel<<<1, 128, 0, stream>>>(bsum, nblk);
    gat_scan3_kernel<<<(n + 255) / 256, 256, 0, stream>>>(deg, incl, bsum, row_ptr, cursor, n);
    gat_scatter_kernel<<<(ne + 255) / 256, 256, 0, stream>>>(srcv, dstv, cursor, col, ne);

    // layer 1: 128 -> 4x16
    gat_gemm_attn_kernel<128, 64, 16><<<(n + 63) / 64, 256, 0, stream>>>(
        x, W1, as1, ad1, buf_h, al_s, al_d, n);
    gat_agg_kernel<16><<<(n + 3) / 4, 256, 0, stream>>>(buf_h, al_s, al_d, row_ptr, col, b1, buf_x, n);

    // layer 2: 64 -> 4x8
    gat_gemm_attn_kernel<64, 32, 16><<<(n + 127) / 128, 256, 0, stream>>>(
        buf_x, W2, as2, ad2, buf_h, al_s, al_d, n);
    gat_agg_kernel<8><<<(n + 3) / 4, 256, 0, stream>>>(buf_h, al_s, al_d, row_ptr, col, b2, buf_x, n);

    // layer 3: 32 -> 4x4
    gat_gemm_attn_kernel<32, 16, 16><<<(n + 255) / 256, 256, 0, stream>>>(
        buf_x, W3, as3, ad3, buf_h, al_s, al_d, n);
    gat_agg_kernel<4><<<(n + 3) / 4, 256, 0, stream>>>(buf_h, al_s, al_d, row_ptr, col, b3, buf_x, n);

    // layer 4: 16 -> 4x2
    gat_gemm_attn_kernel<16, 8, 16><<<(n + 511) / 512, 256, 0, stream>>>(
        buf_x, W4, as4, ad4, buf_h, al_s, al_d, n);
    gat_agg_kernel<2><<<(n + 3) / 4, 256, 0, stream>>>(buf_h, al_s, al_d, row_ptr, col, b4, buf_x, n);

    // global mean pool + FC
    gat_pool_kernel<<<(n + 255) / 256, 256, 0, stream>>>(buf_x, bat, gsum, gcnt, n);
    gat_fc_kernel<<<8, 256, 0, stream>>>(gsum, gcnt, Wfc, bfc, (float*)d_out);
}

// Round 5
// 598.688 us; speedup vs baseline: 1.5529x; 1.2267x over previous
//
#include <hip/hip_runtime.h>
#include <hip/hip_bf16.h>

#define NNODES 100000
#define NEDGES 1600000
#define NHEADS 4
#define NGRAPH 64
#define NOUTF  32

// ---------------- index dtype detect + convert ----------------
// If edge_index arrived as int64 (little-endian, values < 2^31), every odd
// 32-bit word is zero. Random int32 indices make that statistically impossible.
__global__ void gat_detect_kernel(const int* __restrict__ raw, int* __restrict__ flag) {
    __shared__ int any;
    if (threadIdx.x == 0) any = 0;
    __syncthreads();
    int w = raw[threadIdx.x * 2 + 1];   // odd words among first 2048
    if (w != 0) any = 1;                // benign race
    __syncthreads();
    if (threadIdx.x == 0) flag[0] = (any == 0) ? 1 : 0;   // 1 => int64
}

__global__ void gat_cvt_kernel(const int* __restrict__ ei, const int* __restrict__ bt,
                               const int* __restrict__ flag, int* __restrict__ src,
                               int* __restrict__ dst, int* __restrict__ bat, int ne, int n) {
    int i = blockIdx.x * blockDim.x + threadIdx.x;
    bool wide = flag[0] != 0;
    if (i < ne) {
        src[i] = wide ? ei[2 * i] : ei[i];
        dst[i] = wide ? ei[2 * (ne + i)] : ei[ne + i];
    }
    if (i < n) bat[i] = wide ? bt[2 * i] : bt[i];
}

// ---------------- CSR build ----------------
__global__ void gat_hist_kernel(const int* __restrict__ dst, int* __restrict__ deg, int ne) {
    int e = blockIdx.x * blockDim.x + threadIdx.x;
    if (e < ne) atomicAdd(&deg[dst[e]], 1);
}

__global__ void gat_scan1_kernel(const int* __restrict__ deg, int* __restrict__ incl,
                                 int* __restrict__ bsum, int n) {
    __shared__ int sh[1024];
    int i = blockIdx.x * 1024 + threadIdx.x;
    int v = (i < n) ? deg[i] : 0;
    sh[threadIdx.x] = v;
    __syncthreads();
    for (int off = 1; off < 1024; off <<= 1) {
        int t = (threadIdx.x >= off) ? sh[threadIdx.x - off] : 0;
        __syncthreads();
        sh[threadIdx.x] += t;
        __syncthreads();
    }
    if (i < n) incl[i] = sh[threadIdx.x];
    if (threadIdx.x == 1023) bsum[blockIdx.x] = sh[1023];
}

__global__ void gat_scan2_kernel(int* bsum, int nb) {
    __shared__ int sh[128];
    int v = (threadIdx.x < nb) ? bsum[threadIdx.x] : 0;
    sh[threadIdx.x] = v;
    __syncthreads();
    for (int off = 1; off < 128; off <<= 1) {
        int t = (threadIdx.x >= off) ? sh[threadIdx.x - off] : 0;
        __syncthreads();
        sh[threadIdx.x] += t;
        __syncthreads();
    }
    if (threadIdx.x < nb) bsum[threadIdx.x] = sh[threadIdx.x] - v;  // exclusive
}

__global__ void gat_scan3_kernel(const int* __restrict__ deg, const int* __restrict__ incl,
                                 const int* __restrict__ bsum, int* __restrict__ row_ptr,
                                 int* __restrict__ cursor, int n) {
    int i = blockIdx.x * blockDim.x + threadIdx.x;
    if (i < n) {
        int inc = incl[i] + bsum[i >> 10];
        int ex = inc - deg[i];
        row_ptr[i] = ex;
        cursor[i] = ex;
        if (i == n - 1) row_ptr[n] = inc;
    }
}

__global__ void gat_scatter_kernel(const int* __restrict__ src, const int* __restrict__ dst,
                                   int* __restrict__ cursor, int* __restrict__ col, int ne) {
    int e = blockIdx.x * blockDim.x + threadIdx.x;
    if (e < ne) {
        int pos = atomicAdd(&cursor[dst[e]], 1);
        col[pos] = src[e];
    }
}

// ---------------- GEMM + attention coefficients (register-tiled) ----------------
// Block covers NPB nodes x DOUT outputs. Thread computes a 4-node x 4-output
// register tile; all k-loop LDS traffic is ds_read_b128. VALU-bound by design.
__device__ __forceinline__ void fma4(float4& a, float s, const float4& b) {
    a.x += s * b.x;
    a.y += s * b.y;
    a.z += s * b.z;
    a.w += s * b.w;
}

template<int DIN, int DOUT, int KTILE>
__global__ __launch_bounds__(256) void gat_gemm_attn_kernel(
        const float* __restrict__ in, const float* __restrict__ W,
        const float* __restrict__ a_src, const float* __restrict__ a_dst,
        float* __restrict__ h, float* __restrict__ al_s, float* __restrict__ al_d, int n) {
    constexpr int OG = DOUT / 4;       // float4 output groups
    constexpr int NPB = 1024 / OG;     // nodes per block
    constexpr int S = DIN + 4;         // padded node stride (floats, 16B-aligned)
    constexpr int C = DOUT / NHEADS;   // channels per head
    __shared__ float Wl[KTILE * DOUT];
    __shared__ float xs[NPB * S];      // node-major
    const int tid = threadIdx.x;
    const int base = blockIdx.x * NPB;
    constexpr int KC = DIN / 4;
    for (int i = tid; i < NPB * KC; i += 256) {
        int nn = i / KC, kc = i - nn * KC;
        int nd = base + nn;
        float4 v = (nd < n) ? ((const float4*)in)[(size_t)nd * KC + kc]
                            : make_float4(0.f, 0.f, 0.f, 0.f);
        *(float4*)&xs[nn * S + kc * 4] = v;
    }
    const int og = tid % OG;
    const int ng = tid / OG;
    const int n0 = ng * 4;
    float4 acc[4] = {};
    for (int kt = 0; kt < DIN; kt += KTILE) {
        __syncthreads();
        for (int i = tid; i < KTILE * OG; i += 256)
            ((float4*)Wl)[i] = ((const float4*)W)[kt * OG + i];
        __syncthreads();
        #pragma unroll 2
        for (int k = 0; k < KTILE; k += 4) {
            float4 wv[4], xv[4];
            #pragma unroll
            for (int j = 0; j < 4; j++)
                wv[j] = *(const float4*)&Wl[(k + j) * DOUT + og * 4];
            #pragma unroll
            for (int r = 0; r < 4; r++)
                xv[r] = *(const float4*)&xs[(n0 + r) * S + kt + k];
            #pragma unroll
            for (int r = 0; r < 4; r++) {
                fma4(acc[r], xv[r].x, wv[0]);
                fma4(acc[r], xv[r].y, wv[1]);
                fma4(acc[r], xv[r].z, wv[2]);
                fma4(acc[r], xv[r].w, wv[3]);
            }
        }
    }
    float4 asv = ((const float4*)a_src)[og];
    float4 adv = ((const float4*)a_dst)[og];
    #pragma unroll
    for (int r = 0; r < 4; r++) {
        int node = base + n0 + r;
        bool ok = node < n;
        if (ok) ((float4*)h)[(size_t)node * OG + og] = acc[r];
        if constexpr (C >= 4) {
            float ps = acc[r].x * asv.x + acc[r].y * asv.y + acc[r].z * asv.z + acc[r].w * asv.w;
            float pd = acc[r].x * adv.x + acc[r].y * adv.y + acc[r].z * adv.z + acc[r].w * adv.w;
            #pragma unroll
            for (int off = 1; off < C / 4; off <<= 1) {
                ps += __shfl_xor(ps, off);
                pd += __shfl_xor(pd, off);
            }
            if (ok && (og % (C / 4)) == 0) {
                int hh = og / (C / 4);
                al_s[node * NHEADS + hh] = ps;
                al_d[node * NHEADS + hh] = pd;
            }
        } else {  // C == 2: one float4 spans two heads
            if (ok) {
                al_s[node * NHEADS + 2 * og]     = acc[r].x * asv.x + acc[r].y * asv.y;
                al_s[node * NHEADS + 2 * og + 1] = acc[r].z * asv.z + acc[r].w * asv.w;
                al_d[node * NHEADS + 2 * og]     = acc[r].x * adv.x + acc[r].y * adv.y;
                al_d[node * NHEADS + 2 * og + 1] = acc[r].z * adv.z + acc[r].w * adv.w;
            }
        }
    }
}

// ---------------- per-destination-node softmax aggregation ----------------
// One wave per node. Row of G=NHEADS*C floats handled by L=G/4 lanes (float4
// each); NG=64/L edges in flight per iteration.
template<int C>
__global__ __launch_bounds__(256) void gat_agg_kernel(
        const float* __restrict__ h, const float* __restrict__ al_s, const float* __restrict__ al_d,
        const int* __restrict__ row_ptr, const int* __restrict__ col,
        const float* __restrict__ bias, float* __restrict__ out, int n) {
    constexpr int G = NHEADS * C;  // floats per row
    constexpr int L = G / 4;       // lanes per edge group
    constexpr int NG = 64 / L;     // edge groups in flight per wave
    int lane = threadIdx.x & 63;
    int node = blockIdx.x * 4 + (threadIdx.x >> 6);
    if (node >= n) return;
    int sub = lane & (L - 1);
    int g = lane / L;
    int c0 = sub * 4;
    int beg = row_ptr[node];
    int cnt = row_ptr[node + 1] - beg;
    float ald0, ald1;
    if constexpr (C >= 4) {
        ald0 = al_d[node * NHEADS + c0 / C];
        ald1 = ald0;
    } else {
        ald0 = al_d[node * NHEADS + c0 / C];
        ald1 = al_d[node * NHEADS + (c0 + 2) / C];
    }
    const float4* h4 = (const float4*)h;
    float4 acc = make_float4(0.f, 0.f, 0.f, 0.f);
    float ws0 = 0.f, ws1 = 0.f;
    // t == cnt is the implicit self-loop (PyG add_self_loops)
    for (int t = g; t < cnt + 1; t += NG) {
        int src = (t < cnt) ? col[beg + t] : node;
        float4 hv = h4[src * L + sub];
        float w0, w1;
        if constexpr (C >= 4) {
            float e = al_s[src * NHEADS + c0 / C] + ald0;
            e = (e > 0.f) ? e : 0.2f * e;
            w0 = __expf(e);
            w1 = w0;
            ws0 += w0;
        } else {
            float e0 = al_s[src * NHEADS + c0 / C] + ald0;
            float e1 = al_s[src * NHEADS + (c0 + 2) / C] + ald1;
            e0 = (e0 > 0.f) ? e0 : 0.2f * e0;
            e1 = (e1 > 0.f) ? e1 : 0.2f * e1;
            w0 = __expf(e0);
            w1 = __expf(e1);
            ws0 += w0;
            ws1 += w1;
        }
        acc.x += w0 * hv.x;
        acc.y += w0 * hv.y;
        acc.z += w1 * hv.z;
        acc.w += w1 * hv.w;
    }
    #pragma unroll
    for (int off = L; off < 64; off <<= 1) {
        acc.x += __shfl_xor(acc.x, off);
        acc.y += __shfl_xor(acc.y, off);
        acc.z += __shfl_xor(acc.z, off);
        acc.w += __shfl_xor(acc.w, off);
        ws0 += __shfl_xor(ws0, off);
        if constexpr (C < 4) ws1 += __shfl_xor(ws1, off);
    }
    if (g == 0) {
        if constexpr (C >= 4) ws1 = ws0;
        float4 bv = ((const float4*)bias)[sub];
        float4 v;
        v.x = acc.x / (ws0 + 1e-16f) + bv.x;
        v.y = acc.y / (ws0 + 1e-16f) + bv.y;
        v.z = acc.z / (ws1 + 1e-16f) + bv.z;
        v.w = acc.w / (ws1 + 1e-16f) + bv.w;
        v.x = (v.x > 0.f) ? v.x : 0.f;
        v.y = (v.y > 0.f) ? v.y : 0.f;
        v.z = (v.z > 0.f) ? v.z : 0.f;
        v.w = (v.w > 0.f) ? v.w : 0.f;
        ((float4*)out)[node * L + sub] = v;
    }
}

// ---------------- pooling + FC ----------------
__global__ void gat_pool_kernel(const float* __restrict__ x, const int* __restrict__ batch,
                                float* __restrict__ gsum, int* __restrict__ gcnt, int n) {
    __shared__ float bins[NGRAPH * 8];
    __shared__ int cbin[NGRAPH];
    int tid = threadIdx.x;
    for (int i = tid; i < NGRAPH * 8; i += 256) bins[i] = 0.f;
    if (tid < NGRAPH) cbin[tid] = 0;
    __syncthreads();
    int node = blockIdx.x * 256 + tid;
    if (node < n) {
        int b = batch[node];
        atomicAdd(&cbin[b], 1);
        for (int d = 0; d < 8; d++) atomicAdd(&bins[b * 8 + d], x[node * 8 + d]);
    }
    __syncthreads();
    for (int i = tid; i < NGRAPH * 8; i += 256)
        if (bins[i] != 0.f) atomicAdd(&gsum[i], bins[i]);
    if (tid < NGRAPH && cbin[tid]) atomicAdd(&gcnt[tid], cbin[tid]);
}

__global__ void gat_fc_kernel(const float* __restrict__ gsum, const int* __restrict__ gcnt,
                              const float* __restrict__ Wfc, const float* __restrict__ bfc,
                              float* __restrict__ out) {
    int idx = blockIdx.x * 256 + threadIdx.x;
    if (idx >= NGRAPH * NOUTF) return;
    int b = idx / NOUTF, o = idx % NOUTF;
    float c = (float)gcnt[b];
    if (c < 1.f) c = 1.f;
    float acc = bfc[o];
    #pragma unroll
    for (int d = 0; d < 8; d++) acc += (gsum[b * 8 + d] / c) * Wfc[d * NOUTF + o];
    out[idx] = acc;
}

extern "C" void kernel_launch(void* const* d_in, const int* in_sizes, int n_in,
                              void* d_out, int out_size, void* d_ws, size_t ws_size,
                              hipStream_t stream) {
    const float* x = (const float*)d_in[0];
    const int* ei = (const int*)d_in[1];          // [2, E]: row0 = src, row1 = dst
    const int* batch = (const int*)d_in[2];
    const float* W1 = (const float*)d_in[3];
    const float* as1 = (const float*)d_in[4];
    const float* ad1 = (const float*)d_in[5];
    const float* b1 = (const float*)d_in[6];
    const float* W2 = (const float*)d_in[7];
    const float* as2 = (const float*)d_in[8];
    const float* ad2 = (const float*)d_in[9];
    const float* b2 = (const float*)d_in[10];
    const float* W3 = (const float*)d_in[11];
    const float* as3 = (const float*)d_in[12];
    const float* ad3 = (const float*)d_in[13];
    const float* b3 = (const float*)d_in[14];
    const float* W4 = (const float*)d_in[15];
    const float* as4 = (const float*)d_in[16];
    const float* ad4 = (const float*)d_in[17];
    const float* b4 = (const float*)d_in[18];
    const float* Wfc = (const float*)d_in[19];
    const float* bfc = (const float*)d_in[20];

    const int n = NNODES, ne = NEDGES;

    // workspace carve (256B aligned)
    char* p = (char*)d_ws;
    auto carve = [&](size_t bytes) {
        char* r = p;
        p += (bytes + 255) & ~(size_t)255;
        return r;
    };
    int* deg = (int*)carve((size_t)n * 4);
    int* cursor = (int*)carve((size_t)n * 4);
    int* row_ptr = (int*)carve((size_t)(n + 1) * 4);
    int* col = (int*)carve((size_t)ne * 4);
    int* incl = (int*)carve((size_t)n * 4);
    int* bsum = (int*)carve(128 * 4);
    float* buf_h = (float*)carve((size_t)n * 64 * 4);
    float* buf_x = (float*)carve((size_t)n * 64 * 4);
    float* al_s = (float*)carve((size_t)n * NHEADS * 4);
    float* al_d = (float*)carve((size_t)n * NHEADS * 4);
    float* gsum = (float*)carve(NGRAPH * 8 * 4);
    int* gcnt = (int*)carve(NGRAPH * 4);
    int* bat = (int*)carve((size_t)n * 4);
    int* flag = (int*)carve(256);
    // src/dst alias buf_h: consumed by hist/scatter strictly before gemm1 writes buf_h
    int* srcv = (int*)buf_h;
    int* dstv = srcv + ne;

    hipMemsetAsync(deg, 0, (size_t)n * 4, stream);
    hipMemsetAsync(gsum, 0, NGRAPH * 8 * 4, stream);
    hipMemsetAsync(gcnt, 0, NGRAPH * 4, stream);

    // normalize index dtype (int32 vs int64) into srcv/dstv/bat
    gat_detect_kernel<<<1, 1024, 0, stream>>>(ei, flag);
    gat_cvt_kernel<<<(ne + 255) / 256, 256, 0, stream>>>(ei, batch, flag, srcv, dstv, bat, ne, n);

    // CSR by destination, built once, reused by all 4 layers
    gat_hist_kernel<<<(ne + 255) / 256, 256, 0, stream>>>(dstv, deg, ne);
    int nblk = (n + 1023) / 1024;
    gat_scan1_kernel<<<nblk, 1024, 0, stream>>>(deg, incl, bsum, n);
    gat_scan2_kernel<<<1, 128, 0, stream>>>(bsum, nblk);
    gat_scan3_kernel<<<(n + 255) / 256, 256, 0, stream>>>(deg, incl, bsum, row_ptr, cursor, n);
    gat_scatter_kernel<<<(ne + 255) / 256, 256, 0, stream>>>(srcv, dstv, cursor, col, ne);

    // layer 1: 128 -> 4x16
    gat_gemm_attn_kernel<128, 64, 64><<<(n + 63) / 64, 256, 0, stream>>>(
        x, W1, as1, ad1, buf_h, al_s, al_d, n);
    gat_agg_kernel<16><<<(n + 3) / 4, 256, 0, stream>>>(buf_h, al_s, al_d, row_ptr, col, b1, buf_x, n);

    // layer 2: 64 -> 4x8
    gat_gemm_attn_kernel<64, 32, 64><<<(n + 127) / 128, 256, 0, stream>>>(
        buf_x, W2, as2, ad2, buf_h, al_s, al_d, n);
    gat_agg_kernel<8><<<(n + 3) / 4, 256, 0, stream>>>(buf_h, al_s, al_d, row_ptr, col, b2, buf_x, n);

    // layer 3: 32 -> 4x4
    gat_gemm_attn_kernel<32, 16, 32><<<(n + 255) / 256, 256, 0, stream>>>(
        buf_x, W3, as3, ad3, buf_h, al_s, al_d, n);
    gat_agg_kernel<4><<<(n + 3) / 4, 256, 0, stream>>>(buf_h, al_s, al_d, row_ptr, col, b3, buf_x, n);

    // layer 4: 16 -> 4x2
    gat_gemm_attn_kernel<16, 8, 16><<<(n + 511) / 512, 256, 0, stream>>>(
        buf_x, W4, as4, ad4, buf_h, al_s, al_d, n);
    gat_agg_kernel<2><<<(n + 3) / 4, 256, 0, stream>>>(buf_h, al_s, al_d, row_ptr, col, b4, buf_x, n);

    // global mean pool + FC
    gat_pool_kernel<<<(n + 255) / 256, 256, 0, stream>>>(buf_x, bat, gsum, gcnt, n);
    gat_fc_kernel<<<8, 256, 0, stream>>>(gsum, gcnt, Wfc, bfc, (float*)d_out);
}